// Round 6
// baseline (368.204 us; speedup 1.0000x reference)
//
#include <hip/hip_runtime.h>
#include <hip/hip_bf16.h>

// Shapes fixed by the reference: B=8, T=2048, D=1024.
#define BB 8
#define TT 2048
#define DD 1024

typedef __attribute__((ext_vector_type(8))) short short8;
typedef __attribute__((ext_vector_type(4))) float f32x4;
typedef __attribute__((ext_vector_type(4))) unsigned short u16x4;

__device__ inline void gload_lds16(const void* g, void* l) {
    // async global->LDS, width 16B: dest = wave-uniform base + lane*16
    __builtin_amdgcn_global_load_lds((const __attribute__((address_space(1))) void*)g,
                                     (__attribute__((address_space(3))) void*)l, 16, 0, 0);
}

// ---------------------------------------------------------------------------
// Shared 128x128-tile bf16 MFMA GEMM core, BK=64. One call site per kernel.
// 4 waves x 64x64, 16x16x32 MFMA, width-16 global_load_lds staging, 8-chunk
// XOR swizzle (0 bank conflicts, r3 PMC). ~1030 TF in proj3 (r5).
// PACKA: A is packed 128x128 tiles along K (P' triangular storage); caller
//        passes the row-tile base; k-tile kt=k0>>7 at stride 16384 elems.
// PACKC (MODE 1): C is one packed 128x128 tile (ldc ignored, tile-local).
// MODE 0: C[CT] = scale * acc
// MODE 1: C[bf16] = exp(scale*acc) causal-masked; atomicAdd row sums into rs
// MODE 2: C[f32] = acc / rs[row]
// ---------------------------------------------------------------------------
template<int MODE, typename CT, bool PACKA, bool PACKC>
__device__ __forceinline__ void gemm_core(
    const __hip_bfloat16* __restrict__ A,
    const __hip_bfloat16* __restrict__ Bt,
    void* __restrict__ Cbase,
    int lda, int ldb, int ldc,
    int m0, int n0, int kmax,
    float scale, float* __restrict__ rs)
{
    __shared__ __align__(16) __hip_bfloat16 lsA[128 * 64];
    __shared__ __align__(16) __hip_bfloat16 lsB[128 * 64];

    const int t    = threadIdx.x;
    const int w    = t >> 6;
    const int l    = t & 63;
    const int quad = l >> 4;
    const int l16  = l & 15;
    const int wy   = w >> 1;   // wave row (0..1), wave tile 64x64
    const int wx   = w & 1;    // wave col

    f32x4 acc[4][4];
#pragma unroll
    for (int i = 0; i < 4; i++)
#pragma unroll
        for (int j = 0; j < 4; j++) acc[i][j] = f32x4{0.f, 0.f, 0.f, 0.f};

    for (int k0 = 0; k0 < kmax; k0 += 64) {
        // stage A (128x64) and Bt (128x64): 4 rounds x 256 lanes x 16B
#pragma unroll
        for (int p = 0; p < 4; p++) {
            int c   = p * 256 + t;          // slot index 0..1023
            int row = c >> 3;               // 8 slots (chunks) per row
            int gch = (c & 7) ^ (row & 7);  // XOR swizzle
            const __hip_bfloat16* ga;
            if constexpr (PACKA)
                ga = A + ((size_t)(k0 >> 7) * 16384 + row * 128 + (k0 & 64) + gch * 8);
            else
                ga = A + (size_t)(m0 + row) * lda + (k0 + gch * 8);
            const __hip_bfloat16* gb = Bt + (size_t)(n0 + row) * ldb + (k0 + gch * 8);
            char* la = (char*)lsA + p * 4096 + w * 1024;
            char* lb = (char*)lsB + p * 4096 + w * 1024;
            gload_lds16(ga, la);
            gload_lds16(gb, lb);
        }
        __syncthreads();

#pragma unroll
        for (int h = 0; h < 2; h++) {      // two K=32 halves
            short8 aF[4], bF[4];
#pragma unroll
            for (int mf = 0; mf < 4; mf++) {
                int m = wy * 64 + mf * 16 + l16;
                aF[mf] = *(const short8*)((const char*)lsA + m * 128 +
                                          (((h * 4 + quad) ^ (m & 7)) * 16));
            }
#pragma unroll
            for (int nf = 0; nf < 4; nf++) {
                int n = wx * 64 + nf * 16 + l16;
                bF[nf] = *(const short8*)((const char*)lsB + n * 128 +
                                          (((h * 4 + quad) ^ (n & 7)) * 16));
            }
#pragma unroll
            for (int mf = 0; mf < 4; mf++)
#pragma unroll
                for (int nf = 0; nf < 4; nf++)
                    acc[mf][nf] = __builtin_amdgcn_mfma_f32_16x16x32_bf16(
                        aF[mf], bF[nf], acc[mf][nf], 0, 0, 0);
        }
        __syncthreads();
    }

    // epilogue: C/D layout col = lane&15, row = quad*4 + reg
    if constexpr (MODE == 0) {
        CT* C = (CT*)Cbase;
#pragma unroll
        for (int mf = 0; mf < 4; mf++) {
            int rbase = m0 + wy * 64 + mf * 16 + quad * 4;
#pragma unroll
            for (int nf = 0; nf < 4; nf++) {
                int col = n0 + wx * 64 + nf * 16 + l16;
#pragma unroll
                for (int r = 0; r < 4; r++) {
                    float v = acc[mf][nf][r] * scale;
                    if constexpr (sizeof(CT) == 2)
                        C[(size_t)(rbase + r) * ldc + col] = (CT)__float2bfloat16(v);
                    else
                        *((float*)&C[(size_t)(rbase + r) * ldc + col]) = v;
                }
            }
        }
    } else if constexpr (MODE == 1) {
        __hip_bfloat16* C = (__hip_bfloat16*)Cbase;
#pragma unroll
        for (int mf = 0; mf < 4; mf++) {
            int rloc0 = wy * 64 + mf * 16 + quad * 4;
#pragma unroll
            for (int r = 0; r < 4; r++) {
                int rloc = rloc0 + r, row = m0 + rloc;
                float part = 0.f, pv[4];
#pragma unroll
                for (int nf = 0; nf < 4; nf++) {
                    int cloc = wx * 64 + nf * 16 + l16;
                    float e = (n0 + cloc <= row) ? __expf(acc[mf][nf][r] * scale) : 0.f;
                    pv[nf] = e;
                    part += e;
                }
                part += __shfl_xor(part, 1, 64);
                part += __shfl_xor(part, 2, 64);
                part += __shfl_xor(part, 4, 64);
                part += __shfl_xor(part, 8, 64);
                if (l16 == 0) atomicAdd(&rs[row], part);
#pragma unroll
                for (int nf = 0; nf < 4; nf++) {
                    int cloc = wx * 64 + nf * 16 + l16;
                    if constexpr (PACKC)
                        C[rloc * 128 + cloc] = __float2bfloat16(pv[nf]);
                    else
                        C[(size_t)row * ldc + (n0 + cloc)] = __float2bfloat16(pv[nf]);
                }
            }
        }
    } else {
        float* C = (float*)Cbase;
#pragma unroll
        for (int mf = 0; mf < 4; mf++) {
            int rbase = m0 + wy * 64 + mf * 16 + quad * 4;
#pragma unroll
            for (int r = 0; r < 4; r++) {
                int row = rbase + r;
                float inv = 1.f / rs[row];
#pragma unroll
                for (int nf = 0; nf < 4; nf++) {
                    int col = n0 + wx * 64 + nf * 16 + l16;
                    C[(size_t)row * ldc + col] = acc[mf][nf][r] * inv;
                }
            }
        }
    }
}

// ---------------------------------------------------------------------------
// Fused projection: z=0 -> K = x@Wk (ws), z=1 -> Q = x@Wq (into d_out!, dead
// before PV writes), z=2 -> vT2 = Wv^T @ x^T. m-tile of the big operand on
// blockIdx.x -> XCD-local A panels.
// ---------------------------------------------------------------------------
__global__ __launch_bounds__(256, 3) void proj3(
    const __hip_bfloat16* __restrict__ xb,
    const __hip_bfloat16* __restrict__ wt,
    __hip_bfloat16* __restrict__ kk,
    __hip_bfloat16* __restrict__ qq,
    __hip_bfloat16* __restrict__ vT2)
{
    const int z = blockIdx.z;
    const __hip_bfloat16 *A, *Bt;
    void* C;
    int ldc, m0, n0;
    if (z < 2) {
        A = xb; Bt = wt + z * 1048576; C = z ? qq : kk;
        ldc = 1024; m0 = blockIdx.x * 128; n0 = blockIdx.y * 128;
    } else {
        A = wt + 2 * 1048576; Bt = xb; C = vT2;
        ldc = 16384; m0 = blockIdx.y * 128; n0 = blockIdx.x * 128;
    }
    gemm_core<0, __hip_bfloat16, false, false>(A, Bt, C, 1024, 1024, ldc,
                                               m0, n0, 1024, 1.0f, nullptr);
}

#define TRI(i) ((i) * ((i) + 1) / 2)

// ---------------------------------------------------------------------------
// S kernel: P'(packed tri tiles) = exp(Q K^T / 32), row sums -> rsum.
// Exact triangular grid: bx in [0,136) decodes to (mi, ni<=mi); y = batch.
// K constant (1024) -> XCD balance automatic (136 blocks/XCD).
// ---------------------------------------------------------------------------
__global__ __launch_bounds__(256, 3) void s_gemm(
    const __hip_bfloat16* __restrict__ qq,
    const __hip_bfloat16* __restrict__ kk,
    __hip_bfloat16* __restrict__ Pp,
    float* __restrict__ rsum)
{
    int bx = blockIdx.x;                       // 0..135
    int mi = (int)((sqrtf(8.f * bx + 1.f) - 1.f) * 0.5f);
    if (TRI(mi + 1) <= bx) mi++;
    else if (TRI(mi) > bx) mi--;
    int ni = bx - TRI(mi);
    int z = blockIdx.y;

    gemm_core<1, __hip_bfloat16, false, true>(
        qq + (size_t)z * 2097152, kk + (size_t)z * 2097152,
        Pp + (size_t)z * 2228224 + (size_t)(TRI(mi) + ni) * 16384,
        1024, 1024, 0, mi * 128, ni * 128, 1024,
        0.03125f, rsum + (size_t)z * TT);
}

// ---------------------------------------------------------------------------
// PV kernel: out = (P' @ V) / rowsum. permX on bx: XCD d hosts m-tiles
// {15-d, d} -> per-XCD K-tile sum (16-d)+(d+1)=17 const (r4 imbalance fix);
// longest (16-iter) m-tiles dispatch first. A = packed P' row-stripe.
// ---------------------------------------------------------------------------
__global__ __launch_bounds__(256, 3) void pv_gemm(
    const __hip_bfloat16* __restrict__ Pp,
    const __hip_bfloat16* __restrict__ vT2,
    float* __restrict__ out,
    float* __restrict__ rsum)
{
    int bx = blockIdx.x;
    int mi = (bx < 8) ? 15 - bx : bx - 8;
    int m0 = mi * 128;
    int z = blockIdx.z;

    gemm_core<2, float, true, false>(
        Pp + (size_t)z * 2228224 + (size_t)TRI(mi) * 16384,
        vT2 + (size_t)z * 2048,
        out + (size_t)z * 2097152,
        0, 16384, 1024, m0, blockIdx.y * 128, m0 + 128,
        1.0f, rsum + (size_t)z * TT);
}

// ---------------------------------------------------------------------------
// Fused input conversion: blocks [0,16384) -> x fp32->bf16 (4 elems/thread);
// blocks [16384, 16384+3072) -> W transpose+convert (32x32 tiles, 3 matrices).
// ---------------------------------------------------------------------------
__global__ __launch_bounds__(256) void cvt_all(
    const float* __restrict__ x,
    const float* __restrict__ Wk, const float* __restrict__ Wq,
    const float* __restrict__ Wv,
    unsigned short* __restrict__ xb, __hip_bfloat16* __restrict__ wt)
{
    int b = blockIdx.x;
    if (b < 16384) {
        size_t i = ((size_t)b * 256 + threadIdx.x) * 4;
        float4 f = *(const float4*)(x + i);
        union { u16x4 u; __hip_bfloat16 h[4]; } o;
        o.h[0] = __float2bfloat16(f.x);
        o.h[1] = __float2bfloat16(f.y);
        o.h[2] = __float2bfloat16(f.z);
        o.h[3] = __float2bfloat16(f.w);
        *(u16x4*)(xb + i) = o.u;
    } else {
        int bb = b - 16384;                   // 0..3071
        int zz = bb >> 10;                    // matrix select
        int r  = bb & 1023;
        const float* W = zz == 0 ? Wk : (zz == 1 ? Wq : Wv);
        __hip_bfloat16* o = wt + (size_t)zz * DD * DD;
        int h0 = (r & 31) * 32, c0 = (r >> 5) * 32;
        __shared__ float tl[32][33];
        int tx = threadIdx.x & 31, ty = threadIdx.x >> 5;   // 32 x 8
#pragma unroll
        for (int k = 0; k < 4; k++)
            tl[ty + 8 * k][tx] = W[(size_t)(c0 + ty + 8 * k) * DD + h0 + tx];
        __syncthreads();
#pragma unroll
        for (int k = 0; k < 4; k++)
            o[(size_t)(h0 + ty + 8 * k) * DD + c0 + tx] =
                __float2bfloat16(tl[tx][ty + 8 * k]);
    }
}

// ---------------------------------------------------------------------------
extern "C" void kernel_launch(void* const* d_in, const int* in_sizes, int n_in,
                              void* d_out, int out_size, void* d_ws, size_t ws_size,
                              hipStream_t stream)
{
    const float* x  = (const float*)d_in[0];
    const float* Wk = (const float*)d_in[1];
    const float* Wq = (const float*)d_in[2];
    const float* Wv = (const float*)d_in[3];
    float* out = (float*)d_out;

    // workspace layout (bytes), total 109,051,904 (fits: r2 proved >=140.5 MB):
    //   xb  @ 0          : 33,554,432 bf16 (dead after proj3)
    //   P'  @ 0          : 35,651,584 bf16 packed tri tiles, 8 x 136 x 32 KB
    //                      (overlays dead xb)
    //   wt  @ 35,651,584 :  6,291,456 bf16 [k,q,v] (dead after proj3)
    //   rsum@ 35,651,584 :     65,536 fp32 row sums (overlays dead wt)
    //   k   @ 41,943,040 : 33,554,432 bf16
    //   vT2 @ 75,497,472 : 33,554,432 bf16 [d][b*T+t]
    //   q  -> d_out[0:32MB] (fp32 out only written by PV, after q is dead)
    char* ws = (char*)d_ws;
    __hip_bfloat16* xb   = (__hip_bfloat16*)ws;
    __hip_bfloat16* Pp   = (__hip_bfloat16*)ws;
    __hip_bfloat16* wt   = (__hip_bfloat16*)(ws + 35651584);
    float*          rsum = (float*)         (ws + 35651584);
    __hip_bfloat16* kk   = (__hip_bfloat16*)(ws + 41943040);
    __hip_bfloat16* vT2  = (__hip_bfloat16*)(ws + 75497472);
    __hip_bfloat16* qq   = (__hip_bfloat16*)d_out;

    // 1. convert x -> bf16 and W -> transposed bf16 (one dispatch)
    cvt_all<<<16384 + 3072, 256, 0, stream>>>(x, Wk, Wq, Wv,
                                              (unsigned short*)xb, wt);

    // 2. K, Q, vT in one dispatch (z=0,1: x@W; z=2: Wv^T@x^T)
    proj3<<<dim3(128, 8, 3), 256, 0, stream>>>(xb, wt, kk, qq, vT2);

    hipMemsetAsync(rsum, 0, (size_t)BB * TT * 4, stream);

    // 3. P' = exp(Q K^T / 32) packed-triangular; row sums -> rsum. All batches.
    s_gemm<<<dim3(136, 8), 256, 0, stream>>>(qq, kk, Pp, rsum);

    // 4. out = (P' @ V) / rowsum. All batches, causal K-stop via kmax=m0+128.
    pv_gemm<<<dim3(16, 8, 8), 256, 0, stream>>>(Pp, vT2, out, rsum);
}